// Round 2
// baseline (1452.571 us; speedup 1.0000x reference)
//
#include <hip/hip_runtime.h>
#include <math.h>

#define NN 20000
#define EE 640000

__device__ __forceinline__ float lrelu(float x){ return x >= 0.f ? x : 0.2f*x; }

// ---------------- metadata GEMVs: h = m1 @ W_hin + b_hin ; h2 = mt @ W_hout + b_hout
__global__ void k_meta(const float* __restrict__ m1, const float* __restrict__ mt,
                       const float* __restrict__ Whin, const float* __restrict__ bhin,
                       const float* __restrict__ Whout, const float* __restrict__ bhout,
                       float* __restrict__ h, float* __restrict__ h2){
  int j = blockIdx.x*256 + threadIdx.x;
  if (j < 4704) {
    float acc = bhin[j];
    #pragma unroll 8
    for (int k=0;k<64;++k) acc = fmaf(m1[k], Whin[k*4704 + j], acc);
    h[j] = acc;
  } else if (j < 30720) {
    int jj = j - 4704;
    float acc = bhout[jj];
    #pragma unroll 8
    for (int k=0;k<64;++k) acc = fmaf(mt[k], Whout[k*26016 + jj], acc);
    h2[jj] = acc;
  }
}

// ---------------- pack all per-layer params into dense buffer P (22048 floats)
// W1@0(128) B1@128(128) AL1@256(128) AR1@384(128)
// W2@512(4096,[o*128+i]) B2@4608(32) AL2@4640(32) AR2@4672(32)
// W3@4704(4096,[o*32+i]) B3@8800(128) AL3@8928(128) AR3@9056(128)
// W4@9184(4096) B4@13280(32) AL4@13312(32) AR4@13344(32)
// W5@13376(4096) B5@17472(128) AL5@17600(128) AR5@17728(128)
// W6@17856(4096) B6@21952(32) AL6@21984(32) AR6@22016(32)
__global__ void k_pack(const float* __restrict__ h, const float* __restrict__ h2,
                       float* __restrict__ P){
  int t = blockIdx.x*256 + threadIdx.x;
  if (t >= 22048) return;
  const float* a2  = h2;          // 768
  const float* w2  = h2 + 768;    // 12288
  const float* b2  = h2 + 13056;  // 384
  const float* ao2 = h2 + 13440;  // 192
  const float* wo2 = h2 + 13632;  // 12288
  const float* bo2 = h2 + 25920;  // 96
  float v;
  if      (t < 128)   v = h[256 + t];                 // W1 (in=1)
  else if (t < 256)   v = h[384 + (t-128)];           // B1
  else if (t < 384)   v = h[t-256];                   // AL1
  else if (t < 512)   v = h[128 + (t-384)];           // AR1
  else if (t < 4608)  v = h[576 + (t-512)];           // W2 [o*128+i]
  else if (t < 4640)  v = h[4672 + (t-4608)];         // B2
  else if (t < 4672)  v = h[512 + (t-4640)];          // AL2
  else if (t < 4704)  v = h[544 + (t-4672)];          // AR2
  else if (t < 8800)  { int k=t-4704; int o=k>>5, i=k&31;
                        v = w2[(o>>5)*3072 + (o&31)*32 + i]; }        // W3
  else if (t < 8928)  { int o=t-8800; v = b2[(o>>5)*96 + (o&31)]; }   // B3
  else if (t < 9056)  { int q=t-8928;       v = a2[(q>>6)*192 + (q&63)]; } // AL3
  else if (t < 9184)  { int q=(t-9056)+128; v = a2[(q>>6)*192 + (q&63)]; } // AR3
  else if (t < 13280) v = wo2[t-9184];                // W4
  else if (t < 13312) v = bo2[t-13280];               // B4
  else if (t < 13344) v = ao2[t-13312];               // AL4
  else if (t < 13376) v = ao2[32 + (t-13344)];        // AR4
  else if (t < 17472) { int k=t-13376; int o=k>>5, i=k&31;
                        v = w2[(o>>5)*3072 + (32+(o&31))*32 + i]; }   // W5
  else if (t < 17600) { int o=t-17472; v = b2[(o>>5)*96 + 32 + (o&31)]; } // B5
  else if (t < 17728) { int q=t-17600;       v = a2[(q>>6)*192 + 64 + (q&63)]; } // AL5
  else if (t < 17856) { int q=(t-17728)+128; v = a2[(q>>6)*192 + 64 + (q&63)]; } // AR5
  else if (t < 21952) v = wo2[4096 + (t-17856)];      // W6
  else if (t < 21984) v = bo2[32 + (t-21952)];        // B6
  else if (t < 22016) v = ao2[64 + (t-21984)];        // AL6
  else                v = ao2[96 + (t-22016)];        // AR6
  P[t] = v;
}

// ---------------- CSR build
__global__ void k_hist(const int* __restrict__ dst, int* __restrict__ cnt){
  int e = blockIdx.x*256 + threadIdx.x;
  if (e < EE) atomicAdd(&cnt[dst[e]], 1);
}

__global__ __launch_bounds__(1024) void k_scan(const int* __restrict__ cnt,
                                               int* __restrict__ off){
  __shared__ int sums[1024];
  int t = threadIdx.x;
  const int C = 20;
  int lo = t*C, hi = lo+C; if (hi > NN) hi = NN; if (lo > NN) lo = NN;
  int s = 0;
  for (int i=lo;i<hi;++i) s += cnt[i];
  sums[t] = s;
  __syncthreads();
  for (int d=1; d<1024; d<<=1){
    int v = (t>=d) ? sums[t-d] : 0;
    __syncthreads();
    sums[t] += v;
    __syncthreads();
  }
  int excl = (t==0) ? 0 : sums[t-1];
  for (int i=lo;i<hi;++i){ off[i] = excl; excl += cnt[i]; }
  if (t==0) off[NN] = sums[1023];
}

__global__ void k_fill(const int* __restrict__ src, const int* __restrict__ dst,
                       const int* __restrict__ off, int* __restrict__ cnt,
                       int* __restrict__ csr){
  int e = blockIdx.x*256 + threadIdx.x;
  if (e < EE){
    int d = dst[e];
    int p = atomicAdd(&cnt[d], 1);
    csr[off[d] + p] = src[e];
  }
}

// ---------------- feat = z @ W.T   (W dense [OUT][IN] in P)
template<int IN, int OUT>
__global__ __launch_bounds__(256) void k_feat(const float* __restrict__ z,
                                              const float* __restrict__ W,
                                              float* __restrict__ feat){
  __shared__ float Ws[IN*OUT];
  for (int i=threadIdx.x; i<IN*OUT; i+=256) Ws[i] = W[i];
  __syncthreads();
  int tid = blockIdx.x*256 + threadIdx.x;
  int n = tid / OUT, o = tid % OUT;
  if (n >= NN) return;
  const float* zr = z + n*IN;
  const float* wr = Ws + o*IN;
  float acc = 0.f;
  #pragma unroll 8
  for (int i=0;i<IN;++i) acc = fmaf(zr[i], wr[i], acc);
  feat[tid] = acc;
}

// ---------------- el/er per (node, head)
template<int H>
__global__ void k_eler(const float* __restrict__ feat, const float* __restrict__ AL,
                       const float* __restrict__ AR, float* __restrict__ el,
                       float* __restrict__ er){
  int t = blockIdx.x*256 + threadIdx.x;
  if (t >= NN*H) return;
  int h = t % H;
  const float* f = feat + (t/H)*(H*32) + h*32;
  float a = 0.f, b = 0.f;
  #pragma unroll 8
  for (int d=0; d<32; ++d){ float v = f[d]; a = fmaf(v, AL[h*32+d], a); b = fmaf(v, AR[h*32+d], b); }
  el[t] = a; er[t] = b;
}

// ---------------- dead-simple aggregation: one thread per (node, head, dim)
// t = n*(H*32) + h*32 + d ; direct transcription of the reference segment ops.
template<int H, bool ELU>
__global__ __launch_bounds__(256) void k_agg_simple(const int* __restrict__ off,
        const int* __restrict__ csr, const float* __restrict__ feat,
        const float* __restrict__ el, const float* __restrict__ er,
        const float* __restrict__ bias, float* __restrict__ out){
  int t = blockIdx.x*256 + threadIdx.x;
  if (t >= NN*H*32) return;
  int d = t & 31;
  int h = (t >> 5) & (H-1);          // H=1 -> 0
  int n = t / (H*32);
  int start = off[n], end = off[n+1];
  float erl = er[n*H + h];
  // pass 1: segment max
  float m = -INFINITY;
  for (int j=start; j<end; ++j){
    int s = csr[j];
    m = fmaxf(m, lrelu(el[s*H+h] + erl));
  }
  if (end == start) m = 0.f;
  // pass 2: segment sum of exp
  float ssum = 0.f;
  for (int j=start; j<end; ++j){
    int s = csr[j];
    ssum += __expf(lrelu(el[s*H+h] + erl) - m);
  }
  float sinv = 1.f/(ssum + 1e-9f);
  // pass 3: weighted aggregation
  float acc = 0.f;
  for (int j=start; j<end; ++j){
    int s = csr[j];
    float a = __expf(lrelu(el[s*H+h] + erl) - m) * sinv;
    acc = fmaf(a, feat[s*(H*32) + h*32 + d], acc);
  }
  float o = acc + bias[h*32 + d];
  if (ELU) o = o > 0.f ? o : expm1f(o);
  out[t] = o;
}

// ---------------- workspace layout (float elements)
#define WS_H     0
#define WS_H2    4704
#define WS_P     30720
#define WS_EL    52768
#define WS_ER    132768
#define WS_FEAT  212768
#define WS_ZA    2772768
#define WS_ZB    5332768
#define WS_OFFI  5972768
#define WS_OFFT  5992769
#define WS_CNT   6012770
#define WS_CSRI  6032770
#define WS_CSRT  6672770
#define WS_TOTAL 7312770   // floats = 29.25 MB

extern "C" void kernel_launch(void* const* d_in, const int* in_sizes, int n_in,
                              void* d_out, int out_size, void* d_ws, size_t ws_size,
                              hipStream_t stream) {
  // Diagnostic guard: if workspace is too small, emit zeros (-> absmax == max|ref| ~ 185)
  if (ws_size < (size_t)WS_TOTAL * sizeof(float)) {
    hipMemsetAsync(d_out, 0, (size_t)out_size * sizeof(float), stream);
    return;
  }
  const float* X      = (const float*)d_in[0];
  const float* m1     = (const float*)d_in[1];
  const float* mt     = (const float*)d_in[2];
  const float* Whin   = (const float*)d_in[3];
  const float* bhin   = (const float*)d_in[4];
  const float* Whout  = (const float*)d_in[5];
  const float* bhout  = (const float*)d_in[6];
  const int* src_in   = (const int*)d_in[7];
  const int* dst_in   = (const int*)d_in[8];
  const int* src_trg  = (const int*)d_in[9];
  const int* dst_trg  = (const int*)d_in[10];
  float* out = (float*)d_out;
  float* ws  = (float*)d_ws;

  float* h    = ws + WS_H;
  float* h2   = ws + WS_H2;
  float* P    = ws + WS_P;
  float* el   = ws + WS_EL;
  float* er   = ws + WS_ER;
  float* feat = ws + WS_FEAT;
  float* zA   = ws + WS_ZA;
  float* zB   = ws + WS_ZB;
  int* off_in  = (int*)(ws + WS_OFFI);
  int* off_trg = (int*)(ws + WS_OFFT);
  int* cnt     = (int*)(ws + WS_CNT);
  int* csr_in  = (int*)(ws + WS_CSRI);
  int* csr_trg = (int*)(ws + WS_CSRT);

  // params
  k_meta<<<120, 256, 0, stream>>>(m1, mt, Whin, bhin, Whout, bhout, h, h2);
  k_pack<<<87, 256, 0, stream>>>(h, h2, P);

  // CSR for graph "in"
  hipMemsetAsync(cnt, 0, NN*sizeof(int), stream);
  k_hist<<<EE/256, 256, 0, stream>>>(dst_in, cnt);
  k_scan<<<1, 1024, 0, stream>>>(cnt, off_in);
  hipMemsetAsync(cnt, 0, NN*sizeof(int), stream);
  k_fill<<<EE/256, 256, 0, stream>>>(src_in, dst_in, off_in, cnt, csr_in);
  // CSR for graph "trg"
  hipMemsetAsync(cnt, 0, NN*sizeof(int), stream);
  k_hist<<<EE/256, 256, 0, stream>>>(dst_trg, cnt);
  k_scan<<<1, 1024, 0, stream>>>(cnt, off_trg);
  hipMemsetAsync(cnt, 0, NN*sizeof(int), stream);
  k_fill<<<EE/256, 256, 0, stream>>>(src_trg, dst_trg, off_trg, cnt, csr_trg);

  // Layer 1: H=4, in=1 -> zA (N x 128)
  k_feat<1,128><<<(NN*128)/256, 256, 0, stream>>>(X, P+0, feat);
  k_eler<4><<<(NN*4+255)/256, 256, 0, stream>>>(feat, P+256, P+384, el, er);
  k_agg_simple<4,false><<<(NN*128)/256, 256, 0, stream>>>(off_in, csr_in, feat, el, er, P+128, zA);

  // Layer 2: H=1, in=128 -> zB (N x 32), ELU
  k_feat<128,32><<<(NN*32)/256, 256, 0, stream>>>(zA, P+512, feat);
  k_eler<1><<<(NN+255)/256, 256, 0, stream>>>(feat, P+4640, P+4672, el, er);
  k_agg_simple<1,true><<<(NN*32)/256, 256, 0, stream>>>(off_in, csr_in, feat, el, er, P+4608, zB);

  // Layer 3: H=4, in=32 -> zA (N x 128)
  k_feat<32,128><<<(NN*128)/256, 256, 0, stream>>>(zB, P+4704, feat);
  k_eler<4><<<(NN*4+255)/256, 256, 0, stream>>>(feat, P+8928, P+9056, el, er);
  k_agg_simple<4,false><<<(NN*128)/256, 256, 0, stream>>>(off_trg, csr_trg, feat, el, er, P+8800, zA);

  // Layer 4: H=1, in=128 -> zB (N x 32), ELU
  k_feat<128,32><<<(NN*32)/256, 256, 0, stream>>>(zA, P+9184, feat);
  k_eler<1><<<(NN+255)/256, 256, 0, stream>>>(feat, P+13312, P+13344, el, er);
  k_agg_simple<1,true><<<(NN*32)/256, 256, 0, stream>>>(off_trg, csr_trg, feat, el, er, P+13280, zB);

  // Layer 5: H=4, in=32 -> zA (N x 128)
  k_feat<32,128><<<(NN*128)/256, 256, 0, stream>>>(zB, P+13376, feat);
  k_eler<4><<<(NN*4+255)/256, 256, 0, stream>>>(feat, P+17600, P+17728, el, er);
  k_agg_simple<4,false><<<(NN*128)/256, 256, 0, stream>>>(off_trg, csr_trg, feat, el, er, P+17472, zA);

  // Layer 6: H=1, in=128 -> out (N x 32), ELU
  k_feat<128,32><<<(NN*32)/256, 256, 0, stream>>>(zA, P+17856, feat);
  k_eler<1><<<(NN+255)/256, 256, 0, stream>>>(feat, P+21984, P+22016, el, er);
  k_agg_simple<1,true><<<(NN*32)/256, 256, 0, stream>>>(off_trg, csr_trg, feat, el, er, P+21952, out);
}

// Round 3
// 698.280 us; speedup vs baseline: 2.0802x; 2.0802x over previous
//
#include <hip/hip_runtime.h>
#include <math.h>

#define NN 20000
#define EE 640000

__device__ __forceinline__ float lrelu(float x){ return x >= 0.f ? x : 0.2f*x; }

// ---------------- metadata GEMVs
__global__ void k_meta(const float* __restrict__ m1, const float* __restrict__ mt,
                       const float* __restrict__ Whin, const float* __restrict__ bhin,
                       const float* __restrict__ Whout, const float* __restrict__ bhout,
                       float* __restrict__ h, float* __restrict__ h2){
  int j = blockIdx.x*256 + threadIdx.x;
  if (j < 4704) {
    float acc = bhin[j];
    #pragma unroll 8
    for (int k=0;k<64;++k) acc = fmaf(m1[k], Whin[k*4704 + j], acc);
    h[j] = acc;
  } else if (j < 30720) {
    int jj = j - 4704;
    float acc = bhout[jj];
    #pragma unroll 8
    for (int k=0;k<64;++k) acc = fmaf(mt[k], Whout[k*26016 + jj], acc);
    h2[jj] = acc;
  }
}

// ---------------- pack params into P (22048 floats) — verified in round 2
__global__ void k_pack(const float* __restrict__ h, const float* __restrict__ h2,
                       float* __restrict__ P){
  int t = blockIdx.x*256 + threadIdx.x;
  if (t >= 22048) return;
  const float* a2  = h2;          // 768
  const float* w2  = h2 + 768;    // 12288
  const float* b2  = h2 + 13056;  // 384
  const float* ao2 = h2 + 13440;  // 192
  const float* wo2 = h2 + 13632;  // 12288
  const float* bo2 = h2 + 25920;  // 96
  float v;
  if      (t < 128)   v = h[256 + t];
  else if (t < 256)   v = h[384 + (t-128)];
  else if (t < 384)   v = h[t-256];
  else if (t < 512)   v = h[128 + (t-384)];
  else if (t < 4608)  v = h[576 + (t-512)];
  else if (t < 4640)  v = h[4672 + (t-4608)];
  else if (t < 4672)  v = h[512 + (t-4640)];
  else if (t < 4704)  v = h[544 + (t-4672)];
  else if (t < 8800)  { int k=t-4704; int o=k>>5, i=k&31;
                        v = w2[(o>>5)*3072 + (o&31)*32 + i]; }
  else if (t < 8928)  { int o=t-8800; v = b2[(o>>5)*96 + (o&31)]; }
  else if (t < 9056)  { int q=t-8928;       v = a2[(q>>6)*192 + (q&63)]; }
  else if (t < 9184)  { int q=(t-9056)+128; v = a2[(q>>6)*192 + (q&63)]; }
  else if (t < 13280) v = wo2[t-9184];
  else if (t < 13312) v = bo2[t-13280];
  else if (t < 13344) v = ao2[t-13312];
  else if (t < 13376) v = ao2[32 + (t-13344)];
  else if (t < 17472) { int k=t-13376; int o=k>>5, i=k&31;
                        v = w2[(o>>5)*3072 + (32+(o&31))*32 + i]; }
  else if (t < 17600) { int o=t-17472; v = b2[(o>>5)*96 + 32 + (o&31)]; }
  else if (t < 17728) { int q=t-17600;       v = a2[(q>>6)*192 + 64 + (q&63)]; }
  else if (t < 17856) { int q=(t-17728)+128; v = a2[(q>>6)*192 + 64 + (q&63)]; }
  else if (t < 21952) v = wo2[4096 + (t-17856)];
  else if (t < 21984) v = bo2[32 + (t-21952)];
  else if (t < 22016) v = ao2[64 + (t-21984)];
  else                v = ao2[96 + (t-22016)];
  P[t] = v;
}

// cl[h] = dot(W1_h, AL1_h), cr[h] = dot(W1_h, AR1_h)  -> P2[0..3]=cl, P2[4..7]=cr
__global__ void k_l1c(const float* __restrict__ P, float* __restrict__ P2){
  int t = threadIdx.x;
  if (t >= 8) return;
  int h = t >> 1, sel = t & 1;
  const float* W = P;
  const float* A = P + 256 + sel*128;
  float c = 0.f;
  #pragma unroll 8
  for (int d=0; d<32; ++d) c = fmaf(W[h*32+d], A[h*32+d], c);
  P2[sel*4 + h] = c;
}

// ---------------- CSR build
__global__ void k_hist(const int* __restrict__ dst, int* __restrict__ cnt){
  int e = blockIdx.x*256 + threadIdx.x;
  if (e < EE) atomicAdd(&cnt[dst[e]], 1);
}

__global__ __launch_bounds__(1024) void k_scan(const int* __restrict__ cnt,
                                               int* __restrict__ off){
  __shared__ int sums[1024];
  int t = threadIdx.x;
  const int C = 20;
  int lo = t*C, hi = lo+C; if (hi > NN) hi = NN; if (lo > NN) lo = NN;
  int s = 0;
  for (int i=lo;i<hi;++i) s += cnt[i];
  sums[t] = s;
  __syncthreads();
  for (int d=1; d<1024; d<<=1){
    int v = (t>=d) ? sums[t-d] : 0;
    __syncthreads();
    sums[t] += v;
    __syncthreads();
  }
  int excl = (t==0) ? 0 : sums[t-1];
  for (int i=lo;i<hi;++i){ off[i] = excl; excl += cnt[i]; }
  if (t==0) off[NN] = sums[1023];
}

__global__ void k_fill(const int* __restrict__ src, const int* __restrict__ dst,
                       const int* __restrict__ off, int* __restrict__ cnt,
                       int* __restrict__ csr){
  int e = blockIdx.x*256 + threadIdx.x;
  if (e < EE){
    int d = dst[e];
    int p = atomicAdd(&cnt[d], 1);
    csr[off[d] + p] = src[e];
  }
}

// ---------------- feat = z @ W.T  (W [OUT][IN]); LDS holds W transposed (bank-conflict-free)
template<int IN, int OUT>
__global__ __launch_bounds__(256) void k_feat(const float* __restrict__ z,
                                              const float* __restrict__ W,
                                              float* __restrict__ feat){
  __shared__ float Ws[IN*OUT];
  for (int idx=threadIdx.x; idx<IN*OUT; idx+=256){
    int o = idx / IN, i = idx % IN;
    Ws[i*OUT + o] = W[idx];
  }
  __syncthreads();
  int tid = blockIdx.x*256 + threadIdx.x;
  int n = tid / OUT, o = tid % OUT;
  if (n >= NN) return;
  const float* zr = z + n*IN;
  float acc = 0.f;
  #pragma unroll 8
  for (int i=0;i<IN;++i) acc = fmaf(zr[i], Ws[i*OUT + o], acc);
  feat[tid] = acc;
}

// ---------------- el/er per (node, head)
template<int H>
__global__ void k_eler(const float* __restrict__ feat, const float* __restrict__ AL,
                       const float* __restrict__ AR, float* __restrict__ el,
                       float* __restrict__ er){
  int t = blockIdx.x*256 + threadIdx.x;
  if (t >= NN*H) return;
  int h = t % H;
  const float* f = feat + (t/H)*(H*32) + h*32;
  float a = 0.f, b = 0.f;
  #pragma unroll 8
  for (int d=0; d<32; ++d){ float v = f[d]; a = fmaf(v, AL[h*32+d], a); b = fmaf(v, AR[h*32+d], b); }
  el[t] = a; er[t] = b;
}

// ---------------- layer 1 fused (IN=1 algebraic collapse): one wave per node
__global__ __launch_bounds__(256) void k_l1(const int* __restrict__ off,
        const int* __restrict__ csr, const float* __restrict__ X,
        const float* __restrict__ P, const float* __restrict__ P2,
        float* __restrict__ out){
  int wv = threadIdx.x >> 6, l = threadIdx.x & 63;
  int n = blockIdx.x*4 + wv;
  if (n >= NN) return;
  int start = off[n], deg = off[n+1] - start;
  int hl = l & 3, jl = l >> 2;
  float cl = P2[hl], cr = P2[4 + hl];
  float xd = X[n];
  // online softmax with weighted numerator t = sum exp(e-m)*xs
  float m = -INFINITY, ssum = 0.f, t = 0.f;
  for (int j = jl; j < deg; j += 16){
    int s = csr[start + j];
    float xs = X[s];
    float e = lrelu(xs*cl + xd*cr);
    if (e > m){
      float w = __expf(m - e);
      ssum = ssum*w + 1.f;
      t    = t*w + xs;
      m = e;
    } else {
      float w = __expf(e - m);
      ssum += w;
      t    = fmaf(w, xs, t);
    }
  }
  #pragma unroll
  for (int msk=4; msk<64; msk<<=1){
    float mo = __shfl_xor(m, msk), so = __shfl_xor(ssum, msk), to = __shfl_xor(t, msk);
    float mn = fmaxf(m, mo);
    if (mn > -INFINITY){
      float w1 = __expf(m - mn), w2 = __expf(mo - mn);
      ssum = ssum*w1 + so*w2;
      t    = t*w1 + to*w2;
    }
    m = mn;
  }
  float tv = t / (ssum + 1e-9f);
  float th = __shfl(tv, l >> 4);   // head of features 2l,2l+1
  const float2 w2v = *(const float2*)(P + 2*l);        // W1
  const float2 b2v = *(const float2*)(P + 128 + 2*l);  // B1
  float2 o;
  o.x = fmaf(th, w2v.x, b2v.x);
  o.y = fmaf(th, w2v.y, b2v.y);
  *(float2*)(out + n*128 + 2*l) = o;
}

// ---------------- H=4 aggregation v2: one wave per node, 2 sweeps
template<bool ELU>
__global__ __launch_bounds__(256) void k_agg4v2(const int* __restrict__ off,
        const int* __restrict__ csr, const float* __restrict__ feat,
        const float* __restrict__ el, const float* __restrict__ er,
        const float* __restrict__ bias, float* __restrict__ out){
  int wv = threadIdx.x >> 6, l = threadIdx.x & 63;
  int n = blockIdx.x*4 + wv;
  if (n >= NN) return;
  int start = off[n], deg = off[n+1] - start;
  int hl = l & 3, jl = l >> 2;
  float erl = er[n*4 + hl];
  // sweep 1: online max+sum per (head hl), 16 edge-slots in parallel
  float m = -INFINITY, ssum = 0.f;
  for (int j = jl; j < deg; j += 16){
    int s = csr[start + j];
    float e = lrelu(el[s*4 + hl] + erl);
    if (e > m){ ssum = ssum*__expf(m - e) + 1.f; m = e; }
    else        ssum += __expf(e - m);
  }
  #pragma unroll
  for (int msk=4; msk<64; msk<<=1){
    float mo = __shfl_xor(m, msk), so = __shfl_xor(ssum, msk);
    float mn = fmaxf(m, mo);
    if (mn > -INFINITY) ssum = ssum*__expf(m - mn) + so*__expf(mo - mn);
    m = mn;
  }
  float sinv = 1.f/(ssum + 1e-9f);
  // sweep 2: alpha once per (edge, head); accumulate float2 per lane over full row
  int h2l = l >> 4;   // head of features 2l, 2l+1
  float2 acc = make_float2(0.f, 0.f);
  for (int j0 = 0; j0 < deg; j0 += 16){
    int j = j0 + jl;
    int s = 0; float a = 0.f;
    if (j < deg){
      s = csr[start + j];
      a = __expf(lrelu(el[s*4 + hl] + erl) - m) * sinv;
    }
    int cnt = deg - j0; if (cnt > 16) cnt = 16;
    for (int jj = 0; jj < cnt; ++jj){
      int   sj = __shfl(s, jj*4);
      float aj = __shfl(a, jj*4 + h2l);
      const float2 f2 = *(const float2*)(feat + sj*128 + 2*l);
      acc.x = fmaf(aj, f2.x, acc.x);
      acc.y = fmaf(aj, f2.y, acc.y);
    }
  }
  const float2 b2 = *(const float2*)(bias + 2*l);
  float o0 = acc.x + b2.x, o1 = acc.y + b2.y;
  if (ELU){ o0 = o0 > 0.f ? o0 : expm1f(o0); o1 = o1 > 0.f ? o1 : expm1f(o1); }
  *(float2*)(out + n*128 + 2*l) = make_float2(o0, o1);
}

// ---------------- H=1 aggregation v2: one wave per node, 2 sweeps
template<bool ELU>
__global__ __launch_bounds__(256) void k_agg1v2(const int* __restrict__ off,
        const int* __restrict__ csr, const float* __restrict__ feat,
        const float* __restrict__ el, const float* __restrict__ er,
        const float* __restrict__ bias, float* __restrict__ out){
  int wv = threadIdx.x >> 6, l = threadIdx.x & 63;
  int n = blockIdx.x*4 + wv;
  if (n >= NN) return;
  int start = off[n], deg = off[n+1] - start;
  float erl = er[n];
  float m = -INFINITY, ssum = 0.f;
  for (int j = l; j < deg; j += 64){
    float e = lrelu(el[csr[start + j]] + erl);
    if (e > m){ ssum = ssum*__expf(m - e) + 1.f; m = e; }
    else        ssum += __expf(e - m);
  }
  #pragma unroll
  for (int msk=1; msk<64; msk<<=1){
    float mo = __shfl_xor(m, msk), so = __shfl_xor(ssum, msk);
    float mn = fmaxf(m, mo);
    if (mn > -INFINITY) ssum = ssum*__expf(m - mn) + so*__expf(mo - mn);
    m = mn;
  }
  float sinv = 1.f/(ssum + 1e-9f);
  int g = l >> 4, dl = l & 15;  // 4 edge-groups x 16 feature-pair lanes
  float2 acc = make_float2(0.f, 0.f);
  for (int j0 = 0; j0 < deg; j0 += 64){
    int j = j0 + l;
    int s = 0; float a = 0.f;
    if (j < deg){
      s = csr[start + j];
      a = __expf(lrelu(el[s] + erl) - m) * sinv;
    }
    int cnt = deg - j0; if (cnt > 64) cnt = 64;
    for (int jj = 0; jj < cnt; jj += 4){
      int e = jj + g;                    // e<64 always; a==0 pads beyond cnt
      int   sj = __shfl(s, e);
      float aj = __shfl(a, e);
      const float2 f2 = *(const float2*)(feat + sj*32 + 2*dl);
      acc.x = fmaf(aj, f2.x, acc.x);
      acc.y = fmaf(aj, f2.y, acc.y);
    }
  }
  acc.x += __shfl_xor(acc.x, 16); acc.y += __shfl_xor(acc.y, 16);
  acc.x += __shfl_xor(acc.x, 32); acc.y += __shfl_xor(acc.y, 32);
  if (l < 16){
    const float2 b2 = *(const float2*)(bias + 2*l);
    float o0 = acc.x + b2.x, o1 = acc.y + b2.y;
    if (ELU){ o0 = o0 > 0.f ? o0 : expm1f(o0); o1 = o1 > 0.f ? o1 : expm1f(o1); }
    *(float2*)(out + n*32 + 2*l) = make_float2(o0, o1);
  }
}

// ---------------- workspace layout (float elements)
#define WS_H     0
#define WS_H2    4704
#define WS_P     30720
#define WS_P2    52768
#define WS_EL    52776
#define WS_ER    132776
#define WS_FEAT  212776
#define WS_ZA    2772776
#define WS_ZB    5332776
#define WS_OFFI  5972776
#define WS_OFFT  5992777
#define WS_CNT   6012778
#define WS_CSRI  6032778
#define WS_CSRT  6672778
#define WS_TOTAL 7312778

extern "C" void kernel_launch(void* const* d_in, const int* in_sizes, int n_in,
                              void* d_out, int out_size, void* d_ws, size_t ws_size,
                              hipStream_t stream) {
  if (ws_size < (size_t)WS_TOTAL * sizeof(float)) {
    hipMemsetAsync(d_out, 0, (size_t)out_size * sizeof(float), stream);
    return;
  }
  const float* X      = (const float*)d_in[0];
  const float* m1     = (const float*)d_in[1];
  const float* mt     = (const float*)d_in[2];
  const float* Whin   = (const float*)d_in[3];
  const float* bhin   = (const float*)d_in[4];
  const float* Whout  = (const float*)d_in[5];
  const float* bhout  = (const float*)d_in[6];
  const int* src_in   = (const int*)d_in[7];
  const int* dst_in   = (const int*)d_in[8];
  const int* src_trg  = (const int*)d_in[9];
  const int* dst_trg  = (const int*)d_in[10];
  float* out = (float*)d_out;
  float* ws  = (float*)d_ws;

  float* h    = ws + WS_H;
  float* h2   = ws + WS_H2;
  float* P    = ws + WS_P;
  float* P2   = ws + WS_P2;
  float* el   = ws + WS_EL;
  float* er   = ws + WS_ER;
  float* feat = ws + WS_FEAT;
  float* zA   = ws + WS_ZA;
  float* zB   = ws + WS_ZB;
  int* off_in  = (int*)(ws + WS_OFFI);
  int* off_trg = (int*)(ws + WS_OFFT);
  int* cnt     = (int*)(ws + WS_CNT);
  int* csr_in  = (int*)(ws + WS_CSRI);
  int* csr_trg = (int*)(ws + WS_CSRT);

  // params
  k_meta<<<120, 256, 0, stream>>>(m1, mt, Whin, bhin, Whout, bhout, h, h2);
  k_pack<<<87, 256, 0, stream>>>(h, h2, P);
  k_l1c<<<1, 64, 0, stream>>>(P, P2);

  // CSR "in"
  hipMemsetAsync(cnt, 0, NN*sizeof(int), stream);
  k_hist<<<EE/256, 256, 0, stream>>>(dst_in, cnt);
  k_scan<<<1, 1024, 0, stream>>>(cnt, off_in);
  hipMemsetAsync(cnt, 0, NN*sizeof(int), stream);
  k_fill<<<EE/256, 256, 0, stream>>>(src_in, dst_in, off_in, cnt, csr_in);
  // CSR "trg"
  hipMemsetAsync(cnt, 0, NN*sizeof(int), stream);
  k_hist<<<EE/256, 256, 0, stream>>>(dst_trg, cnt);
  k_scan<<<1, 1024, 0, stream>>>(cnt, off_trg);
  hipMemsetAsync(cnt, 0, NN*sizeof(int), stream);
  k_fill<<<EE/256, 256, 0, stream>>>(src_trg, dst_trg, off_trg, cnt, csr_trg);

  const int NB4 = (NN + 3) / 4;

  // Layer 1: fused (H=4, in=1) -> zA (N x 128)
  k_l1<<<NB4, 256, 0, stream>>>(off_in, csr_in, X, P, P2, zA);

  // Layer 2: H=1, in=128 -> zB (N x 32), ELU
  k_feat<128,32><<<(NN*32)/256, 256, 0, stream>>>(zA, P+512, feat);
  k_eler<1><<<(NN+255)/256, 256, 0, stream>>>(feat, P+4640, P+4672, el, er);
  k_agg1v2<true><<<NB4, 256, 0, stream>>>(off_in, csr_in, feat, el, er, P+4608, zB);

  // Layer 3: H=4, in=32 -> zA (N x 128)
  k_feat<32,128><<<(NN*128)/256, 256, 0, stream>>>(zB, P+4704, feat);
  k_eler<4><<<(NN*4+255)/256, 256, 0, stream>>>(feat, P+8928, P+9056, el, er);
  k_agg4v2<false><<<NB4, 256, 0, stream>>>(off_trg, csr_trg, feat, el, er, P+8800, zA);

  // Layer 4: H=1, in=128 -> zB (N x 32), ELU
  k_feat<128,32><<<(NN*32)/256, 256, 0, stream>>>(zA, P+9184, feat);
  k_eler<1><<<(NN+255)/256, 256, 0, stream>>>(feat, P+13312, P+13344, el, er);
  k_agg1v2<true><<<NB4, 256, 0, stream>>>(off_trg, csr_trg, feat, el, er, P+13280, zB);

  // Layer 5: H=4, in=32 -> zA (N x 128)
  k_feat<32,128><<<(NN*128)/256, 256, 0, stream>>>(zB, P+13376, feat);
  k_eler<4><<<(NN*4+255)/256, 256, 0, stream>>>(feat, P+17600, P+17728, el, er);
  k_agg4v2<false><<<NB4, 256, 0, stream>>>(off_trg, csr_trg, feat, el, er, P+17472, zA);

  // Layer 6: H=1, in=128 -> out (N x 32), ELU
  k_feat<128,32><<<(NN*32)/256, 256, 0, stream>>>(zA, P+17856, feat);
  k_eler<1><<<(NN+255)/256, 256, 0, stream>>>(feat, P+21984, P+22016, el, er);
  k_agg1v2<true><<<NB4, 256, 0, stream>>>(off_trg, csr_trg, feat, el, er, P+21952, out);
}

// Round 4
// 540.973 us; speedup vs baseline: 2.6851x; 1.2908x over previous
//
#include <hip/hip_runtime.h>
#include <math.h>

#define NN 20000
#define EE 640000

__device__ __forceinline__ float lrelu(float x){ return x >= 0.f ? x : 0.2f*x; }

// ---------------- metadata GEMVs
__global__ void k_meta(const float* __restrict__ m1, const float* __restrict__ mt,
                       const float* __restrict__ Whin, const float* __restrict__ bhin,
                       const float* __restrict__ Whout, const float* __restrict__ bhout,
                       float* __restrict__ h, float* __restrict__ h2){
  int j = blockIdx.x*256 + threadIdx.x;
  if (j < 4704) {
    float acc = bhin[j];
    #pragma unroll 8
    for (int k=0;k<64;++k) acc = fmaf(m1[k], Whin[k*4704 + j], acc);
    h[j] = acc;
  } else if (j < 30720) {
    int jj = j - 4704;
    float acc = bhout[jj];
    #pragma unroll 8
    for (int k=0;k<64;++k) acc = fmaf(mt[k], Whout[k*26016 + jj], acc);
    h2[jj] = acc;
  }
}

// ---------------- pack params into P (22048 floats) — verified
__global__ void k_pack(const float* __restrict__ h, const float* __restrict__ h2,
                       float* __restrict__ P){
  int t = blockIdx.x*256 + threadIdx.x;
  if (t >= 22048) return;
  const float* a2  = h2;          // 768
  const float* w2  = h2 + 768;    // 12288
  const float* b2  = h2 + 13056;  // 384
  const float* ao2 = h2 + 13440;  // 192
  const float* wo2 = h2 + 13632;  // 12288
  const float* bo2 = h2 + 25920;  // 96
  float v;
  if      (t < 128)   v = h[256 + t];
  else if (t < 256)   v = h[384 + (t-128)];
  else if (t < 384)   v = h[t-256];
  else if (t < 512)   v = h[128 + (t-384)];
  else if (t < 4608)  v = h[576 + (t-512)];
  else if (t < 4640)  v = h[4672 + (t-4608)];
  else if (t < 4672)  v = h[512 + (t-4640)];
  else if (t < 4704)  v = h[544 + (t-4672)];
  else if (t < 8800)  { int k=t-4704; int o=k>>5, i=k&31;
                        v = w2[(o>>5)*3072 + (o&31)*32 + i]; }
  else if (t < 8928)  { int o=t-8800; v = b2[(o>>5)*96 + (o&31)]; }
  else if (t < 9056)  { int q=t-8928;       v = a2[(q>>6)*192 + (q&63)]; }
  else if (t < 9184)  { int q=(t-9056)+128; v = a2[(q>>6)*192 + (q&63)]; }
  else if (t < 13280) v = wo2[t-9184];
  else if (t < 13312) v = bo2[t-13280];
  else if (t < 13344) v = ao2[t-13312];
  else if (t < 13376) v = ao2[32 + (t-13344)];
  else if (t < 17472) { int k=t-13376; int o=k>>5, i=k&31;
                        v = w2[(o>>5)*3072 + (32+(o&31))*32 + i]; }
  else if (t < 17600) { int o=t-17472; v = b2[(o>>5)*96 + 32 + (o&31)]; }
  else if (t < 17728) { int q=t-17600;       v = a2[(q>>6)*192 + 64 + (q&63)]; }
  else if (t < 17856) { int q=(t-17728)+128; v = a2[(q>>6)*192 + 64 + (q&63)]; }
  else if (t < 21952) v = wo2[4096 + (t-17856)];
  else if (t < 21984) v = bo2[32 + (t-21952)];
  else if (t < 22016) v = ao2[64 + (t-21984)];
  else                v = ao2[96 + (t-22016)];
  P[t] = v;
}

// cl[h] = dot(W1_h, AL1_h), cr[h] = dot(W1_h, AR1_h)  -> P2[0..3]=cl, P2[4..7]=cr
__global__ void k_l1c(const float* __restrict__ P, float* __restrict__ P2){
  int t = threadIdx.x;
  if (t >= 8) return;
  int h = t >> 1, sel = t & 1;
  const float* W = P;
  const float* A = P + 256 + sel*128;
  float c = 0.f;
  #pragma unroll 8
  for (int d=0; d<32; ++d) c = fmaf(W[h*32+d], A[h*32+d], c);
  P2[sel*4 + h] = c;
}

// ---------------- CSR build
__global__ void k_hist(const int* __restrict__ dst, int* __restrict__ cnt){
  int e = blockIdx.x*256 + threadIdx.x;
  if (e < EE) atomicAdd(&cnt[dst[e]], 1);
}

__global__ __launch_bounds__(1024) void k_scan(const int* __restrict__ cnt,
                                               int* __restrict__ off){
  __shared__ int sums[1024];
  int t = threadIdx.x;
  const int C = 20;
  int lo = t*C, hi = lo+C; if (hi > NN) hi = NN; if (lo > NN) lo = NN;
  int s = 0;
  for (int i=lo;i<hi;++i) s += cnt[i];
  sums[t] = s;
  __syncthreads();
  for (int d=1; d<1024; d<<=1){
    int v = (t>=d) ? sums[t-d] : 0;
    __syncthreads();
    sums[t] += v;
    __syncthreads();
  }
  int excl = (t==0) ? 0 : sums[t-1];
  for (int i=lo;i<hi;++i){ off[i] = excl; excl += cnt[i]; }
  if (t==0) off[NN] = sums[1023];
}

__global__ void k_fill(const int* __restrict__ src, const int* __restrict__ dst,
                       const int* __restrict__ off, int* __restrict__ cnt,
                       int* __restrict__ csr){
  int e = blockIdx.x*256 + threadIdx.x;
  if (e < EE){
    int d = dst[e];
    int p = atomicAdd(&cnt[d], 1);
    csr[off[d] + p] = src[e];
  }
}

// ---------------- fused feat+el/er: feat = z @ W.T, then per-(n,h) attention dots
// LDS weight tile padded (+1) -> conflict-free writes and reads.
// 32-lane group == one (n,h) pair (dout=32 always); butterfly-reduce within group.
template<int IN, int OUT, int H>
__global__ __launch_bounds__(256) void k_featel(const float* __restrict__ z,
        const float* __restrict__ W, const float* __restrict__ AL,
        const float* __restrict__ AR, float* __restrict__ feat,
        float* __restrict__ el, float* __restrict__ er){
  __shared__ float Ws[IN*(OUT+1)];
  __shared__ float ALs[OUT], ARs[OUT];
  for (int idx=threadIdx.x; idx<IN*OUT; idx+=256){
    int o = idx / IN, i = idx % IN;
    Ws[i*(OUT+1) + o] = W[idx];
  }
  for (int idx=threadIdx.x; idx<OUT; idx+=256){ ALs[idx]=AL[idx]; ARs[idx]=AR[idx]; }
  __syncthreads();
  int tid = blockIdx.x*256 + threadIdx.x;
  int n = tid / OUT, o = tid % OUT;
  const float4* z4 = (const float4*)(z + n*IN);
  float acc = 0.f;
  #pragma unroll
  for (int i=0;i<IN/4;++i){
    float4 zv = z4[i];
    acc = fmaf(zv.x, Ws[(4*i+0)*(OUT+1)+o], acc);
    acc = fmaf(zv.y, Ws[(4*i+1)*(OUT+1)+o], acc);
    acc = fmaf(zv.z, Ws[(4*i+2)*(OUT+1)+o], acc);
    acc = fmaf(zv.w, Ws[(4*i+3)*(OUT+1)+o], acc);
  }
  feat[tid] = acc;
  float a = acc * ALs[o], b = acc * ARs[o];
  #pragma unroll
  for (int msk=1; msk<32; msk<<=1){
    a += __shfl_xor(a, msk);
    b += __shfl_xor(b, msk);
  }
  if ((o & 31) == 0){
    int h = o >> 5;
    el[n*H + h] = a;
    er[n*H + h] = b;
  }
}

// ---------------- layer 1 fused (IN=1 algebraic collapse): one wave per node
__global__ __launch_bounds__(256) void k_l1(const int* __restrict__ off,
        const int* __restrict__ csr, const float* __restrict__ X,
        const float* __restrict__ P, const float* __restrict__ P2,
        float* __restrict__ out){
  int wv = threadIdx.x >> 6, l = threadIdx.x & 63;
  int n = blockIdx.x*4 + wv;
  if (n >= NN) return;
  int start = off[n], deg = off[n+1] - start;
  int hl = l & 3, jl = l >> 2;
  float cl = P2[hl], cr = P2[4 + hl];
  float xd = X[n];
  float m = -INFINITY, ssum = 0.f, t = 0.f;
  for (int j = jl; j < deg; j += 16){
    int s = csr[start + j];
    float xs = X[s];
    float e = lrelu(xs*cl + xd*cr);
    if (e > m){
      float w = __expf(m - e);
      ssum = ssum*w + 1.f;
      t    = t*w + xs;
      m = e;
    } else {
      float w = __expf(e - m);
      ssum += w;
      t    = fmaf(w, xs, t);
    }
  }
  #pragma unroll
  for (int msk=4; msk<64; msk<<=1){
    float mo = __shfl_xor(m, msk), so = __shfl_xor(ssum, msk), to = __shfl_xor(t, msk);
    float mn = fmaxf(m, mo);
    if (mn > -INFINITY){
      float w1 = __expf(m - mn), w2 = __expf(mo - mn);
      ssum = ssum*w1 + so*w2;
      t    = t*w1 + to*w2;
    }
    m = mn;
  }
  float tv = t / (ssum + 1e-9f);
  float th = __shfl(tv, l >> 4);
  const float2 w2v = *(const float2*)(P + 2*l);
  const float2 b2v = *(const float2*)(P + 128 + 2*l);
  float2 o;
  o.x = fmaf(th, w2v.x, b2v.x);
  o.y = fmaf(th, w2v.y, b2v.y);
  *(float2*)(out + n*128 + 2*l) = o;
}

// ---------------- H=4 aggregation: one wave per node, 2 sweeps
template<bool ELU>
__global__ __launch_bounds__(256) void k_agg4v2(const int* __restrict__ off,
        const int* __restrict__ csr, const float* __restrict__ feat,
        const float* __restrict__ el, const float* __restrict__ er,
        const float* __restrict__ bias, float* __restrict__ out){
  int wv = threadIdx.x >> 6, l = threadIdx.x & 63;
  int n = blockIdx.x*4 + wv;
  if (n >= NN) return;
  int start = off[n], deg = off[n+1] - start;
  int hl = l & 3, jl = l >> 2;
  float erl = er[n*4 + hl];
  float m = -INFINITY, ssum = 0.f;
  for (int j = jl; j < deg; j += 16){
    int s = csr[start + j];
    float e = lrelu(el[s*4 + hl] + erl);
    if (e > m){ ssum = ssum*__expf(m - e) + 1.f; m = e; }
    else        ssum += __expf(e - m);
  }
  #pragma unroll
  for (int msk=4; msk<64; msk<<=1){
    float mo = __shfl_xor(m, msk), so = __shfl_xor(ssum, msk);
    float mn = fmaxf(m, mo);
    if (mn > -INFINITY) ssum = ssum*__expf(m - mn) + so*__expf(mo - mn);
    m = mn;
  }
  float sinv = 1.f/(ssum + 1e-9f);
  int h2l = l >> 4;
  float2 acc = make_float2(0.f, 0.f);
  for (int j0 = 0; j0 < deg; j0 += 16){
    int j = j0 + jl;
    int s = 0; float a = 0.f;
    if (j < deg){
      s = csr[start + j];
      a = __expf(lrelu(el[s*4 + hl] + erl) - m) * sinv;
    }
    int cnt = deg - j0; if (cnt > 16) cnt = 16;
    for (int jj = 0; jj < cnt; ++jj){
      int   sj = __shfl(s, jj*4);
      float aj = __shfl(a, jj*4 + h2l);
      const float2 f2 = *(const float2*)(feat + sj*128 + 2*l);
      acc.x = fmaf(aj, f2.x, acc.x);
      acc.y = fmaf(aj, f2.y, acc.y);
    }
  }
  const float2 b2 = *(const float2*)(bias + 2*l);
  float o0 = acc.x + b2.x, o1 = acc.y + b2.y;
  if (ELU){ o0 = o0 > 0.f ? o0 : expm1f(o0); o1 = o1 > 0.f ? o1 : expm1f(o1); }
  *(float2*)(out + n*128 + 2*l) = make_float2(o0, o1);
}

// ---------------- H=1 aggregation: one wave per node, 2 sweeps
template<bool ELU>
__global__ __launch_bounds__(256) void k_agg1v2(const int* __restrict__ off,
        const int* __restrict__ csr, const float* __restrict__ feat,
        const float* __restrict__ el, const float* __restrict__ er,
        const float* __restrict__ bias, float* __restrict__ out){
  int wv = threadIdx.x >> 6, l = threadIdx.x & 63;
  int n = blockIdx.x*4 + wv;
  if (n >= NN) return;
  int start = off[n], deg = off[n+1] - start;
  float erl = er[n];
  float m = -INFINITY, ssum = 0.f;
  for (int j = l; j < deg; j += 64){
    float e = lrelu(el[csr[start + j]] + erl);
    if (e > m){ ssum = ssum*__expf(m - e) + 1.f; m = e; }
    else        ssum += __expf(e - m);
  }
  #pragma unroll
  for (int msk=1; msk<64; msk<<=1){
    float mo = __shfl_xor(m, msk), so = __shfl_xor(ssum, msk);
    float mn = fmaxf(m, mo);
    if (mn > -INFINITY) ssum = ssum*__expf(m - mn) + so*__expf(mo - mn);
    m = mn;
  }
  float sinv = 1.f/(ssum + 1e-9f);
  int g = l >> 4, dl = l & 15;
  float2 acc = make_float2(0.f, 0.f);
  for (int j0 = 0; j0 < deg; j0 += 64){
    int j = j0 + l;
    int s = 0; float a = 0.f;
    if (j < deg){
      s = csr[start + j];
      a = __expf(lrelu(el[s] + erl) - m) * sinv;
    }
    int cnt = deg - j0; if (cnt > 64) cnt = 64;
    for (int jj = 0; jj < cnt; jj += 4){
      int e = jj + g;
      int   sj = __shfl(s, e);
      float aj = __shfl(a, e);
      const float2 f2 = *(const float2*)(feat + sj*32 + 2*dl);
      acc.x = fmaf(aj, f2.x, acc.x);
      acc.y = fmaf(aj, f2.y, acc.y);
    }
  }
  acc.x += __shfl_xor(acc.x, 16); acc.y += __shfl_xor(acc.y, 16);
  acc.x += __shfl_xor(acc.x, 32); acc.y += __shfl_xor(acc.y, 32);
  if (l < 16){
    const float2 b2 = *(const float2*)(bias + 2*l);
    float o0 = acc.x + b2.x, o1 = acc.y + b2.y;
    if (ELU){ o0 = o0 > 0.f ? o0 : expm1f(o0); o1 = o1 > 0.f ? o1 : expm1f(o1); }
    *(float2*)(out + n*32 + 2*l) = make_float2(o0, o1);
  }
}

// ---------------- workspace layout (float elements)
#define WS_H     0
#define WS_H2    4704
#define WS_P     30720
#define WS_P2    52768
#define WS_EL    52776
#define WS_ER    132776
#define WS_FEAT  212776
#define WS_ZA    2772776
#define WS_ZB    5332776
#define WS_OFFI  5972776
#define WS_OFFT  5992777
#define WS_CNT   6012778
#define WS_CSRI  6032778
#define WS_CSRT  6672778
#define WS_TOTAL 7312778

extern "C" void kernel_launch(void* const* d_in, const int* in_sizes, int n_in,
                              void* d_out, int out_size, void* d_ws, size_t ws_size,
                              hipStream_t stream) {
  if (ws_size < (size_t)WS_TOTAL * sizeof(float)) {
    hipMemsetAsync(d_out, 0, (size_t)out_size * sizeof(float), stream);
    return;
  }
  const float* X      = (const float*)d_in[0];
  const float* m1     = (const float*)d_in[1];
  const float* mt     = (const float*)d_in[2];
  const float* Whin   = (const float*)d_in[3];
  const float* bhin   = (const float*)d_in[4];
  const float* Whout  = (const float*)d_in[5];
  const float* bhout  = (const float*)d_in[6];
  const int* src_in   = (const int*)d_in[7];
  const int* dst_in   = (const int*)d_in[8];
  const int* src_trg  = (const int*)d_in[9];
  const int* dst_trg  = (const int*)d_in[10];
  float* out = (float*)d_out;
  float* ws  = (float*)d_ws;

  float* h    = ws + WS_H;
  float* h2   = ws + WS_H2;
  float* P    = ws + WS_P;
  float* P2   = ws + WS_P2;
  float* el   = ws + WS_EL;
  float* er   = ws + WS_ER;
  float* feat = ws + WS_FEAT;
  float* zA   = ws + WS_ZA;
  float* zB   = ws + WS_ZB;
  int* off_in  = (int*)(ws + WS_OFFI);
  int* off_trg = (int*)(ws + WS_OFFT);
  int* cnt     = (int*)(ws + WS_CNT);
  int* csr_in  = (int*)(ws + WS_CSRI);
  int* csr_trg = (int*)(ws + WS_CSRT);

  // params
  k_meta<<<120, 256, 0, stream>>>(m1, mt, Whin, bhin, Whout, bhout, h, h2);
  k_pack<<<87, 256, 0, stream>>>(h, h2, P);
  k_l1c<<<1, 64, 0, stream>>>(P, P2);

  // CSR "in"
  hipMemsetAsync(cnt, 0, NN*sizeof(int), stream);
  k_hist<<<EE/256, 256, 0, stream>>>(dst_in, cnt);
  k_scan<<<1, 1024, 0, stream>>>(cnt, off_in);
  hipMemsetAsync(cnt, 0, NN*sizeof(int), stream);
  k_fill<<<EE/256, 256, 0, stream>>>(src_in, dst_in, off_in, cnt, csr_in);
  // CSR "trg"
  hipMemsetAsync(cnt, 0, NN*sizeof(int), stream);
  k_hist<<<EE/256, 256, 0, stream>>>(dst_trg, cnt);
  k_scan<<<1, 1024, 0, stream>>>(cnt, off_trg);
  hipMemsetAsync(cnt, 0, NN*sizeof(int), stream);
  k_fill<<<EE/256, 256, 0, stream>>>(src_trg, dst_trg, off_trg, cnt, csr_trg);

  const int NB4 = (NN + 3) / 4;

  // Layer 1: fused (H=4, in=1) -> zA (N x 128)
  k_l1<<<NB4, 256, 0, stream>>>(off_in, csr_in, X, P, P2, zA);

  // Layer 2: H=1, in=128 -> zB (N x 32), ELU
  k_featel<128,32,1><<<(NN*32)/256, 256, 0, stream>>>(zA, P+512, P+4640, P+4672, feat, el, er);
  k_agg1v2<true><<<NB4, 256, 0, stream>>>(off_in, csr_in, feat, el, er, P+4608, zB);

  // Layer 3: H=4, in=32 -> zA (N x 128)
  k_featel<32,128,4><<<(NN*128)/256, 256, 0, stream>>>(zB, P+4704, P+8928, P+9056, feat, el, er);
  k_agg4v2<false><<<NB4, 256, 0, stream>>>(off_trg, csr_trg, feat, el, er, P+8800, zA);

  // Layer 4: H=1, in=128 -> zB (N x 32), ELU
  k_featel<128,32,1><<<(NN*32)/256, 256, 0, stream>>>(zA, P+9184, P+13312, P+13344, feat, el, er);
  k_agg1v2<true><<<NB4, 256, 0, stream>>>(off_trg, csr_trg, feat, el, er, P+13280, zB);

  // Layer 5: H=4, in=32 -> zA (N x 128)
  k_featel<32,128,4><<<(NN*128)/256, 256, 0, stream>>>(zB, P+13376, P+17600, P+17728, feat, el, er);
  k_agg4v2<false><<<NB4, 256, 0, stream>>>(off_trg, csr_trg, feat, el, er, P+17472, zA);

  // Layer 6: H=1, in=128 -> out (N x 32), ELU
  k_featel<128,32,1><<<(NN*32)/256, 256, 0, stream>>>(zA, P+17856, P+21984, P+22016, feat, el, er);
  k_agg1v2<true><<<NB4, 256, 0, stream>>>(off_trg, csr_trg, feat, el, er, P+21952, out);
}

// Round 6
// 506.543 us; speedup vs baseline: 2.8676x; 1.0680x over previous
//
#include <hip/hip_runtime.h>
#include <math.h>

#define NN 20000
#define EE 640000

__device__ __forceinline__ float lrelu(float x){ return x >= 0.f ? x : 0.2f*x; }

// ---------------- fused metadata GEMV + pack: P[t] directly (22048 floats)
// P layout: W1@0(128) B1@128 AL1@256 AR1@384
// W2@512(4096) B2@4608 AL2@4640 AR2@4672
// W3@4704(4096) B3@8800 AL3@8928 AR3@9056
// W4@9184(4096) B4@13280 AL4@13312 AR4@13344
// W5@13376(4096) B5@17472 AL5@17600 AR5@17728
// W6@17856(4096) B6@21952 AL6@21984 AR6@22016
__global__ void k_param(const float* __restrict__ m1, const float* __restrict__ mt,
                        const float* __restrict__ Whin, const float* __restrict__ bhin,
                        const float* __restrict__ Whout, const float* __restrict__ bhout,
                        float* __restrict__ P){
  int t = blockIdx.x*256 + threadIdx.x;
  if (t >= 22048) return;
  int sj; bool inA;
  if      (t < 128)  { sj = 256+t;          inA=true; }
  else if (t < 256)  { sj = 384+(t-128);    inA=true; }
  else if (t < 384)  { sj = t-256;          inA=true; }
  else if (t < 512)  { sj = 128+(t-384);    inA=true; }
  else if (t < 4608) { sj = 576+(t-512);    inA=true; }
  else if (t < 4640) { sj = 4672+(t-4608);  inA=true; }
  else if (t < 4672) { sj = 512+(t-4640);   inA=true; }
  else if (t < 4704) { sj = 544+(t-4672);   inA=true; }
  else { inA=false;
    // h2 segment bases: a2@0 w2@768 b2@13056 ao2@13440 wo2@13632 bo2@25920
    if      (t < 8800)  { int k=t-4704, o=k>>5, i=k&31; sj = 768 + (o>>5)*3072+(o&31)*32+i; }
    else if (t < 8928)  { int o=t-8800; sj = 13056 + (o>>5)*96+(o&31); }
    else if (t < 9056)  { int q=t-8928;       sj = (q>>6)*192+(q&63); }
    else if (t < 9184)  { int q=(t-9056)+128; sj = (q>>6)*192+(q&63); }
    else if (t < 13280) { sj = 13632 + (t-9184); }
    else if (t < 13312) { sj = 25920 + (t-13280); }
    else if (t < 13344) { sj = 13440 + (t-13312); }
    else if (t < 13376) { sj = 13472 + (t-13344); }
    else if (t < 17472) { int k=t-13376, o=k>>5, i=k&31; sj = 768 + (o>>5)*3072+(32+(o&31))*32+i; }
    else if (t < 17600) { int o=t-17472; sj = 13056 + (o>>5)*96+32+(o&31); }
    else if (t < 17728) { int q=t-17600;       sj = (q>>6)*192+64+(q&63); }
    else if (t < 17856) { int q=(t-17728)+128; sj = (q>>6)*192+64+(q&63); }
    else if (t < 21952) { sj = 13632+4096+(t-17856); }
    else if (t < 21984) { sj = 25920+32+(t-21952); }
    else if (t < 22016) { sj = 13440+64+(t-21984); }
    else                { sj = 13440+96+(t-22016); }
  }
  float acc;
  if (inA){
    acc = bhin[sj];
    #pragma unroll 8
    for (int k=0;k<64;++k) acc = fmaf(m1[k], Whin[k*4704 + sj], acc);
  } else {
    acc = bhout[sj];
    #pragma unroll 8
    for (int k=0;k<64;++k) acc = fmaf(mt[k], Whout[k*26016 + sj], acc);
  }
  P[t] = acc;
}

// ---------------- CSR build (both graphs in one pass)
__global__ void k_hist2(const int* __restrict__ dst_in, const int* __restrict__ dst_trg,
                        int* __restrict__ cnt2){
  int e = blockIdx.x*256 + threadIdx.x;
  if (e < EE)        atomicAdd(&cnt2[dst_in[e]], 1);
  else if (e < 2*EE) atomicAdd(&cnt2[NN + dst_trg[e-EE]], 1);
}

// blocks 0,1: scan halves of cnt2 -> off arrays; cnt2 := exclusive prefix (fill allocator)
// block 2: P2[0..3]=dot(W1_h,AL1_h), P2[4..7]=dot(W1_h,AR1_h)
__global__ __launch_bounds__(1024) void k_scan2(int* __restrict__ cnt2,
        int* __restrict__ off_in, int* __restrict__ off_trg,
        const float* __restrict__ P, float* __restrict__ P2){
  int b = blockIdx.x;
  if (b == 2){
    int t = threadIdx.x;
    if (t < 8){
      int hh = t >> 1, sel = t & 1;
      const float* W = P;
      const float* A = P + 256 + sel*128;
      float c = 0.f;
      #pragma unroll 8
      for (int d=0; d<32; ++d) c = fmaf(W[hh*32+d], A[hh*32+d], c);
      P2[sel*4 + hh] = c;
    }
    return;
  }
  int* cnt = cnt2 + b*NN;
  int* off = b ? off_trg : off_in;
  __shared__ int sums[1024];
  int t = threadIdx.x;
  const int C = 20;
  int lo = t*C, hi = lo+C; if (hi > NN) hi = NN;
  int s = 0;
  for (int i=lo; i<hi; ++i) s += cnt[i];
  sums[t] = s;
  __syncthreads();
  for (int d=1; d<1024; d<<=1){
    int v = (t>=d) ? sums[t-d] : 0;
    __syncthreads();
    sums[t] += v;
    __syncthreads();
  }
  int excl = (t==0) ? 0 : sums[t-1];
  for (int i=lo; i<hi; ++i){
    int c = cnt[i];
    off[i] = excl;
    cnt[i] = excl;   // allocator for fill
    excl += c;
  }
  if (t==0) off[NN] = sums[1023];
}

__global__ void k_fill2(const int* __restrict__ src_in, const int* __restrict__ dst_in,
                        const int* __restrict__ src_trg, const int* __restrict__ dst_trg,
                        int* __restrict__ cnt2, int* __restrict__ csr_in,
                        int* __restrict__ csr_trg){
  int e = blockIdx.x*256 + threadIdx.x;
  if (e < EE){
    int p = atomicAdd(&cnt2[dst_in[e]], 1);
    csr_in[p] = src_in[e];
  } else if (e < 2*EE){
    int p = atomicAdd(&cnt2[NN + dst_trg[e-EE]], 1);
    csr_trg[p] = src_trg[e-EE];
  }
}

// ---------------- fused feat+el/er (LDS padded, verified R4)
template<int IN, int OUT, int H>
__global__ __launch_bounds__(256) void k_featel(const float* __restrict__ z,
        const float* __restrict__ W, const float* __restrict__ AL,
        const float* __restrict__ AR, float* __restrict__ feat,
        float* __restrict__ el, float* __restrict__ er){
  __shared__ float Ws[IN*(OUT+1)];
  __shared__ float ALs[OUT], ARs[OUT];
  for (int idx=threadIdx.x; idx<IN*OUT; idx+=256){
    int o = idx / IN, i = idx % IN;
    Ws[i*(OUT+1) + o] = W[idx];
  }
  for (int idx=threadIdx.x; idx<OUT; idx+=256){ ALs[idx]=AL[idx]; ARs[idx]=AR[idx]; }
  __syncthreads();
  int tid = blockIdx.x*256 + threadIdx.x;
  int n = tid / OUT, o = tid % OUT;
  const float4* z4 = (const float4*)(z + n*IN);
  float acc = 0.f;
  #pragma unroll
  for (int i=0;i<IN/4;++i){
    float4 zv = z4[i];
    acc = fmaf(zv.x, Ws[(4*i+0)*(OUT+1)+o], acc);
    acc = fmaf(zv.y, Ws[(4*i+1)*(OUT+1)+o], acc);
    acc = fmaf(zv.z, Ws[(4*i+2)*(OUT+1)+o], acc);
    acc = fmaf(zv.w, Ws[(4*i+3)*(OUT+1)+o], acc);
  }
  feat[tid] = acc;
  float a = acc * ALs[o], b = acc * ARs[o];
  #pragma unroll
  for (int msk=1; msk<32; msk<<=1){
    a += __shfl_xor(a, msk);
    b += __shfl_xor(b, msk);
  }
  if ((o & 31) == 0){
    int h = o >> 5;
    el[n*H + h] = a;
    er[n*H + h] = b;
  }
}

// ---------------- layer 1 fused (IN=1 algebraic collapse)
__global__ __launch_bounds__(256) void k_l1(const int* __restrict__ off,
        const int* __restrict__ csr, const float* __restrict__ X,
        const float* __restrict__ P, const float* __restrict__ P2,
        float* __restrict__ out){
  int wv = threadIdx.x >> 6, l = threadIdx.x & 63;
  int n = blockIdx.x*4 + wv;
  if (n >= NN) return;
  int start = off[n], deg = off[n+1] - start;
  int hl = l & 3, jl = l >> 2;
  float cl = P2[hl], cr = P2[4 + hl];
  float xd = X[n];
  float m = -INFINITY, ssum = 0.f, t = 0.f;
  for (int j = jl; j < deg; j += 16){
    int s = csr[start + j];
    float xs = X[s];
    float e = lrelu(xs*cl + xd*cr);
    if (e > m){
      float w = __expf(m - e);
      ssum = ssum*w + 1.f;
      t    = t*w + xs;
      m = e;
    } else {
      float w = __expf(e - m);
      ssum += w;
      t    = fmaf(w, xs, t);
    }
  }
  #pragma unroll
  for (int msk=4; msk<64; msk<<=1){
    float mo = __shfl_xor(m, msk), so = __shfl_xor(ssum, msk), to = __shfl_xor(t, msk);
    float mn = fmaxf(m, mo);
    if (mn > -INFINITY){
      float w1 = __expf(m - mn), w2 = __expf(mo - mn);
      ssum = ssum*w1 + so*w2;
      t    = t*w1 + to*w2;
    }
    m = mn;
  }
  float tv = t / (ssum + 1e-9f);
  float th = __shfl(tv, l >> 4);
  const float2 w2v = *(const float2*)(P + 2*l);
  const float2 b2v = *(const float2*)(P + 128 + 2*l);
  float2 o;
  o.x = fmaf(th, w2v.x, b2v.x);
  o.y = fmaf(th, w2v.y, b2v.y);
  *(float2*)(out + n*128 + 2*l) = o;
}

// ---------------- unified aggregation: one wave per (node, head). grid (NB4, H)
// Sweep1: 64 lanes over edges (online max+sum). Sweep2: 4 edge-groups x 16 lanes x float2.
// NOTE: sweep-2 inner loop bound MUST be wave-uniform (jj from 0, e=jj+g): per-lane
// bounds make lanes exit at different trips and __shfl from an exited (inactive)
// lane is undefined on CDNA (ds_bpermute) — this was R5's correctness bug.
template<int H, bool ELU>
__global__ __launch_bounds__(256) void k_aggH(const int* __restrict__ off,
        const int* __restrict__ csr, const float* __restrict__ feat,
        const float* __restrict__ el, const float* __restrict__ er,
        const float* __restrict__ bias, float* __restrict__ out){
  int wv = threadIdx.x >> 6, l = threadIdx.x & 63;
  int n = blockIdx.x*4 + wv;
  if (n >= NN) return;
  int h = blockIdx.y;
  int start = off[n], deg = off[n+1] - start;
  float erl = er[n*H + h];
  float m = -INFINITY, ssum = 0.f;
  for (int j = l; j < deg; j += 64){
    float e = lrelu(el[csr[start + j]*H + h] + erl);
    if (e > m){ ssum = ssum*__expf(m - e) + 1.f; m = e; }
    else        ssum += __expf(e - m);
  }
  #pragma unroll
  for (int msk=1; msk<64; msk<<=1){
    float mo = __shfl_xor(m, msk), so = __shfl_xor(ssum, msk);
    float mn = fmaxf(m, mo);
    if (mn > -INFINITY) ssum = ssum*__expf(m - mn) + so*__expf(mo - mn);
    m = mn;
  }
  float sinv = 1.f/(ssum + 1e-9f);
  int g = l >> 4, dl = l & 15;
  float2 acc = make_float2(0.f, 0.f);
  for (int j0 = 0; j0 < deg; j0 += 64){
    int j = j0 + l;
    int s = 0; float a = 0.f;
    if (j < deg){
      s = csr[start + j];
      a = __expf(lrelu(el[s*H + h] + erl) - m) * sinv;
    }
    int cnt = deg - j0; if (cnt > 64) cnt = 64;
    for (int jj = 0; jj < cnt; jj += 4){     // uniform trip count across the wave
      int e = jj + g;                        // e <= 60+3 = 63; a==0 pads e >= cnt
      int   sj = __shfl(s, e);
      float aj = __shfl(a, e);
      const float2 f2 = *(const float2*)(feat + sj*(H*32) + h*32 + 2*dl);
      acc.x = fmaf(aj, f2.x, acc.x);
      acc.y = fmaf(aj, f2.y, acc.y);
    }
  }
  acc.x += __shfl_xor(acc.x, 16); acc.y += __shfl_xor(acc.y, 16);
  acc.x += __shfl_xor(acc.x, 32); acc.y += __shfl_xor(acc.y, 32);
  if (l < 16){
    const float2 b2 = *(const float2*)(bias + h*32 + 2*l);
    float o0 = acc.x + b2.x, o1 = acc.y + b2.y;
    if (ELU){ o0 = o0 > 0.f ? o0 : expm1f(o0); o1 = o1 > 0.f ? o1 : expm1f(o1); }
    *(float2*)(out + n*(H*32) + h*32 + 2*l) = make_float2(o0, o1);
  }
}

// ---------------- workspace layout (float elements)
#define WS_P     0
#define WS_P2    22048
#define WS_EL    22056
#define WS_ER    102056
#define WS_FEAT  182056
#define WS_ZA    2742056
#define WS_ZB    5302056
#define WS_OFFI  5942056
#define WS_OFFT  5962057
#define WS_CNT   5982058
#define WS_CSRI  6022058
#define WS_CSRT  6662058
#define WS_TOTAL 7302058   // 29.2 MB

extern "C" void kernel_launch(void* const* d_in, const int* in_sizes, int n_in,
                              void* d_out, int out_size, void* d_ws, size_t ws_size,
                              hipStream_t stream) {
  if (ws_size < (size_t)WS_TOTAL * sizeof(float)) {
    hipMemsetAsync(d_out, 0, (size_t)out_size * sizeof(float), stream);
    return;
  }
  const float* X      = (const float*)d_in[0];
  const float* m1     = (const float*)d_in[1];
  const float* mt     = (const float*)d_in[2];
  const float* Whin   = (const float*)d_in[3];
  const float* bhin   = (const float*)d_in[4];
  const float* Whout  = (const float*)d_in[5];
  const float* bhout  = (const float*)d_in[6];
  const int* src_in   = (const int*)d_in[7];
  const int* dst_in   = (const int*)d_in[8];
  const int* src_trg  = (const int*)d_in[9];
  const int* dst_trg  = (const int*)d_in[10];
  float* out = (float*)d_out;
  float* ws  = (float*)d_ws;

  float* P    = ws + WS_P;
  float* P2   = ws + WS_P2;
  float* el   = ws + WS_EL;
  float* er   = ws + WS_ER;
  float* feat = ws + WS_FEAT;
  float* zA   = ws + WS_ZA;
  float* zB   = ws + WS_ZB;
  int* off_in  = (int*)(ws + WS_OFFI);
  int* off_trg = (int*)(ws + WS_OFFT);
  int* cnt2    = (int*)(ws + WS_CNT);
  int* csr_in  = (int*)(ws + WS_CSRI);
  int* csr_trg = (int*)(ws + WS_CSRT);

  // params (fused GEMV+pack)
  k_param<<<87, 256, 0, stream>>>(m1, mt, Whin, bhin, Whout, bhout, P);

  // CSR for both graphs
  hipMemsetAsync(cnt2, 0, 2*NN*sizeof(int), stream);
  k_hist2<<<2*EE/256, 256, 0, stream>>>(dst_in, dst_trg, cnt2);
  k_scan2<<<3, 1024, 0, stream>>>(cnt2, off_in, off_trg, P, P2);
  k_fill2<<<2*EE/256, 256, 0, stream>>>(src_in, dst_in, src_trg, dst_trg, cnt2, csr_in, csr_trg);

  const int NB4 = (NN + 3) / 4;
  dim3 g4(NB4, 4), g1(NB4, 1);

  // Layer 1: fused (H=4, in=1) -> zA (N x 128)
  k_l1<<<NB4, 256, 0, stream>>>(off_in, csr_in, X, P, P2, zA);

  // Layer 2: H=1, in=128 -> zB (N x 32), ELU
  k_featel<128,32,1><<<(NN*32)/256, 256, 0, stream>>>(zA, P+512, P+4640, P+4672, feat, el, er);
  k_aggH<1,true><<<g1, 256, 0, stream>>>(off_in, csr_in, feat, el, er, P+4608, zB);

  // Layer 3: H=4, in=32 -> zA (N x 128)
  k_featel<32,128,4><<<(NN*128)/256, 256, 0, stream>>>(zB, P+4704, P+8928, P+9056, feat, el, er);
  k_aggH<4,false><<<g4, 256, 0, stream>>>(off_trg, csr_trg, feat, el, er, P+8800, zA);

  // Layer 4: H=1, in=128 -> zB (N x 32), ELU
  k_featel<128,32,1><<<(NN*32)/256, 256, 0, stream>>>(zA, P+9184, P+13312, P+13344, feat, el, er);
  k_aggH<1,true><<<g1, 256, 0, stream>>>(off_trg, csr_trg, feat, el, er, P+13280, zB);

  // Layer 5: H=4, in=32 -> zA (N x 128)
  k_featel<32,128,4><<<(NN*128)/256, 256, 0, stream>>>(zB, P+13376, P+17600, P+17728, feat, el, er);
  k_aggH<4,false><<<g4, 256, 0, stream>>>(off_trg, csr_trg, feat, el, er, P+17472, zA);

  // Layer 6: H=1, in=128 -> out (N x 32), ELU
  k_featel<128,32,1><<<(NN*32)/256, 256, 0, stream>>>(zA, P+17856, P+21984, P+22016, feat, el, er);
  k_aggH<1,true><<<g1, 256, 0, stream>>>(off_trg, csr_trg, feat, el, er, P+21952, out);
}